// Round 1
// baseline (138.931 us; speedup 1.0000x reference)
//
#include <hip/hip_runtime.h>
#include <math.h>

#define NN 10000
#define NE 160000
#define CAP 96   // per-node edge bin capacity; deg ~ Poisson(16), +20 sigma
// Only the l=0 irrep reaches the output (scal takes cols h*72..h*72+8 of pooled,
// which come solely from node_out[:,:,0]; Y[:,0]==1). l=1/l=2 paths are dead.
//
// Round 8: the per-edge 64-wide hidden MLP depends only on scalar f (d or 1/d^2):
//   sum_j relu(a_j f + b_j) * w_j  is piecewise-LINEAR in f (64 breakpoints).
// Precompute per-segment slope/intercept tables (A,B per channel + att channel)
// in k_xqk block 0 (sort thresholds + prefix walk); k_edge does a 7-step binary
// search + 16 FMA instead of the 1152-FMA hidden loop per head. Exact math
// (fp32 reassociation only). Everything else identical to Round 7.
//
// Table layout per head (floats, TPH=2432 stride):
//   [0..63]      sorted thresholds
//   [64..128]    Aatt[65]
//   [132..196]   Batt[65]
//   [200..1304]  A[65][17]  (stride 17 = bank-conflict padding)
//   [1312..2416] B[65][17]
#define TPH 2432
#define AATT_OFF 64
#define BATT_OFF 132
#define A_OFF 200
#define B_OFF 1312

// Workspace (floats):
//   x      [10000][16]        @ 0
//   q      [10000][2][16]     @ 160000
//   k      [10000][2][16]     @ 480000
//   feat   [10000][16]        @ 800000
//   pooled [16][16]           @ 960000
//   deg    int[10000]         @ 960256   (pooled..deg zeroed together)
//   tab    [2][2432]          @ 970256   piecewise-linear tables
//   lgp    [10000][96][2]     fp32 logits
//   gb     [10000][96][2][4]  uint bf16x2-packed g[8] per head

__device__ __forceinline__ unsigned bf16pack2(float a, float b) {
    unsigned ua = __float_as_uint(a);
    unsigned ub = __float_as_uint(b);
    ua = ua + 0x7fffu + ((ua >> 16) & 1u);
    ub = ub + 0x7fffu + ((ub >> 16) & 1u);
    return (ua >> 16) | (ub & 0xffff0000u);
}

// x = nf @ We + be ; q[h] = x @ Wq[h] ; k[h] = x @ Wk[h]
// block 0 also builds the piecewise-linear ReLU tables; all blocks zero pooled+deg.
__global__ __launch_bounds__(256) void k_xqk(const float* __restrict__ nf,
        const float* __restrict__ We, const float* __restrict__ be,
        const float* __restrict__ Wq, const float* __restrict__ Wk,
        const float* __restrict__ W1, const float* __restrict__ b1,
        const float* __restrict__ Wa, const float* __restrict__ Wv,
        float* __restrict__ x, float* __restrict__ q, float* __restrict__ k,
        int* __restrict__ zeroReg, float* __restrict__ tab) {
    int t = threadIdx.x;
    int gid = blockIdx.x * 256 + t;
    if (gid < 10256) zeroReg[gid] = 0;   // pooled(256f)+deg(10000i), contiguous
    __shared__ float sWe[64 * 16];
    __shared__ float sWq[2 * 16 * 16];
    __shared__ float sWk[2 * 16 * 16];
    __shared__ float sNF[16 * 64];
    __shared__ float sX[16 * 16];
    // table-build scratch (touched by block 0 only)
    __shared__ float sT[2][64], sDA[2][64], sDB[2][64], sIA[2][64], sIB[2][64];
    __shared__ float sW[2][64][17];   // per-unit channel weights; c==16 -> Wa
    __shared__ short sOrd[2][64];
    for (int i = t; i < 1024; i += 256) sWe[i] = We[i];
    for (int i = t; i < 512; i += 256) { sWq[i] = Wq[i]; sWk[i] = Wk[i]; }
    int nodeBase = blockIdx.x * 16;
    for (int i = t; i < 1024; i += 256) {
        int n = nodeBase + (i >> 6);
        sNF[i] = (n < NN) ? nf[n * 64 + (i & 63)] : 0.0f;
    }
    __syncthreads();
    int ln = t >> 4, c = t & 15;
    int n = nodeBase + ln;
    float acc = be[c];
    #pragma unroll 16
    for (int j = 0; j < 64; ++j) acc = fmaf(sNF[ln * 64 + j], sWe[j * 16 + c], acc);
    sX[ln * 16 + c] = acc;
    __syncthreads();
    if (n < NN) {
        x[n * 16 + c] = acc;
        #pragma unroll
        for (int h = 0; h < 2; ++h) {
            float aq = 0.0f, ak = 0.0f;
            #pragma unroll
            for (int j = 0; j < 16; ++j) {
                float xv = sX[ln * 16 + j];
                aq = fmaf(xv, sWq[(h * 16 + j) * 16 + c], aq);
                ak = fmaf(xv, sWk[(h * 16 + j) * 16 + c], ak);
            }
            q[(n * 2 + h) * 16 + c] = aq;
            k[(n * 2 + h) * 16 + c] = ak;
        }
    }
    if (blockIdx.x == 0) {
        // ---- phase A: per-unit threshold, toggle deltas, init contributions ----
        if (t < 128) {
            int h = t >> 6, j = t & 63;
            float a = W1[h * 64 + j], b = b1[h * 64 + j];
            float da = 0.0f, db = 0.0f, ia = 0.0f, ib = 0.0f, th;
            if (a > 0.0f)      { th = -b / a; da = a;  db = b; }          // turns ON crossing th
            else if (a < 0.0f) { th = -b / a; da = -a; db = -b; ia = a; ib = b; } // ON below th
            else               { th = INFINITY; if (b > 0.0f) ib = b; }   // constant
            sT[h][j] = th; sDA[h][j] = da; sDB[h][j] = db; sIA[h][j] = ia; sIB[h][j] = ib;
        }
        for (int i = t; i < 2 * 64 * 17; i += 256) {
            int h = i / 1088, r = i % 1088, j = r / 17, cc = r % 17;
            sW[h][j][cc] = (cc < 16) ? Wv[(h * 64 + j) * 48 + 3 * cc] : Wa[h * 64 + j];
        }
        __syncthreads();
        // ---- phase B: rank-sort thresholds (64-wide O(n^2), trivial) ----
        if (t < 128) {
            int h = t >> 6, j = t & 63;
            float tj = sT[h][j];
            int r = 0;
            #pragma unroll 16
            for (int kk = 0; kk < 64; ++kk) {
                float tk = sT[h][kk];
                r += (tk < tj || (tk == tj && kk < j)) ? 1 : 0;
            }
            sOrd[h][r] = (short)j;
            tab[h * TPH + r] = tj;          // sorted thresholds
        }
        __syncthreads();
        // ---- phase C: prefix walk over sorted order; store A/B per segment ----
        if (t < 34) {
            int h = t / 17, cc = t % 17;
            float A = 0.0f, B = 0.0f;
            #pragma unroll 8
            for (int j = 0; j < 64; ++j) {   // active set at f = -inf
                float w = sW[h][j][cc];
                A = fmaf(sIA[h][j], w, A);
                B = fmaf(sIB[h][j], w, B);
            }
            float* pa; float* pb; int stride;
            if (cc == 16) { pa = tab + h * TPH + AATT_OFF; pb = tab + h * TPH + BATT_OFF; stride = 1; }
            else          { pa = tab + h * TPH + A_OFF + cc; pb = tab + h * TPH + B_OFF + cc; stride = 17; }
            pa[0] = A; pb[0] = B;
            #pragma unroll 8
            for (int sg = 1; sg <= 64; ++sg) {
                int u = sOrd[h][sg - 1];
                float w = sW[h][u][cc];
                A = fmaf(sDA[h][u], w, A);
                B = fmaf(sDB[h][u], w, B);
                pa[sg * stride] = A;
                pb[sg * stride] = B;
            }
        }
    }
}

// one thread per edge: logits + g[o] via piecewise-linear table lookup,
// bin slot tgt*CAP+p. Payload bf16x2-packed.
__global__ __launch_bounds__(256) void k_edge(const float* __restrict__ pos,
        const int* __restrict__ ei,
        const float* __restrict__ q, const float* __restrict__ k,
        const float* __restrict__ Wo, const float* __restrict__ x,
        const float* __restrict__ tab, int* __restrict__ deg,
        float* __restrict__ lgp, uint4* __restrict__ gb) {
    __shared__ float sTab[2 * TPH];
    int tid = threadIdx.x;
    for (int i = tid; i < 2 * TPH; i += 256) sTab[i] = tab[i];
    __syncthreads();
    int e = blockIdx.x * 256 + tid;
    if (e >= NE) return;
    int s = ei[e], t = ei[NE + e];
    int p = atomicAdd(&deg[t], 1);
    bool ok = (p < CAP);
    size_t slot = (size_t)t * CAP + p;
    float dx = pos[t * 3 + 0] - pos[s * 3 + 0];
    float dy = pos[t * 3 + 1] - pos[s * 3 + 1];
    float dz = pos[t * 3 + 2] - pos[s * 3 + 2];
    float d = sqrtf(dx * dx + dy * dy + dz * dz);
    float fh2[2] = { d, 1.0f / (d * d) };
    const float4* xp = (const float4*)(x + (size_t)s * 16);
    float4 xs0 = xp[0], xs1 = xp[1], xs2 = xp[2], xs3 = xp[3];
    float xf[16] = { xs0.x, xs0.y, xs0.z, xs0.w, xs1.x, xs1.y, xs1.z, xs1.w,
                     xs2.x, xs2.y, xs2.z, xs2.w, xs3.x, xs3.y, xs3.z, xs3.w };
    float L2v[2];
    #pragma unroll
    for (int h = 0; h < 2; ++h) {
        const float4* qt = (const float4*)(q + (size_t)t * 32 + h * 16);
        const float4* ks = (const float4*)(k + (size_t)s * 32 + h * 16);
        float4 a0 = qt[0], a1 = qt[1], a2 = qt[2], a3 = qt[3];
        float4 b0 = ks[0], c1 = ks[1], c2 = ks[2], c3 = ks[3];
        float dot = a0.x * b0.x + a0.y * b0.y + a0.z * b0.z + a0.w * b0.w
                  + a1.x * c1.x + a1.y * c1.y + a1.z * c1.z + a1.w * c1.w
                  + a2.x * c2.x + a2.y * c2.y + a2.z * c2.z + a2.w * c2.w
                  + a3.x * c3.x + a3.y * c3.y + a3.z * c3.z + a3.w * c3.w;
        float f = fh2[h];
        const float* tb = sTab + h * TPH;
        // branchless lower_bound: sg = #{ thresholds < f }, 0..64
        int sg = 0;
        #pragma unroll
        for (int st = 32; st >= 1; st >>= 1)
            if (tb[sg + st - 1] < f) sg += st;
        if (tb[sg] < f) ++sg;
        float att = fmaf(tb[AATT_OFF + sg], f, tb[BATT_OFF + sg]);
        L2v[h] = fmaf(dot, 0.25f, att);
        const float* Ab = tb + A_OFF + sg * 17;
        const float* Bb = tb + B_OFF + sg * 17;
        const float* wob = Wo + h * 384;   // Wo[h][0][c][o] = Wo[h*384 + c*8 + o]
        float g[8];
        #pragma unroll
        for (int o = 0; o < 8; ++o) g[o] = 0.0f;
        #pragma unroll
        for (int c = 0; c < 16; ++c) {
            float axc = fmaf(Ab[c], f, Bb[c]) * xf[c];   // acc[c] * x[src][c]
            #pragma unroll
            for (int o = 0; o < 8; ++o) g[o] = fmaf(axc, wob[c * 8 + o], g[o]);
        }
        if (ok) {
            gb[slot * 2 + h] = make_uint4(bf16pack2(g[0], g[1]), bf16pack2(g[2], g[3]),
                                          bf16pack2(g[4], g[5]), bf16pack2(g[6], g[7]));
        }
    }
    if (ok) *(float2*)(lgp + slot * 2) = make_float2(L2v[0], L2v[1]);
}

// wave per (node,head): 16 edge-groups x 4 lanes x 2 outputs (bf16x2 unpack),
// single-pass online softmax, -inf-safe merges.
__global__ __launch_bounds__(256) void k_gather(const int* __restrict__ deg,
        const float* __restrict__ lgp, const unsigned* __restrict__ gb,
        float* __restrict__ feat) {
    int t0 = threadIdx.x;
    int wv = t0 >> 6;                     // wave in block 0..3
    int lane = t0 & 63;
    int pid = blockIdx.x * 4 + wv;        // (node,head) pair; grid exact
    int n = pid >> 1, h = pid & 1;
    int dg = min(deg[n], CAP);
    int g = lane >> 2, p = lane & 3;      // group 0..15, uint index 0..3
    float m = -INFINITY, z = 0.0f, u0 = 0.0f, u1 = 0.0f;
    const float* lgb = lgp + (size_t)n * (CAP * 2) + h;
    const unsigned* gbb = gb + (size_t)n * (CAP * 8) + h * 4 + p;
    for (int i = g; i < dg; i += 16) {
        float L = lgb[i * 2];
        unsigned wbits = gbb[(size_t)i * 8];
        float ga = __uint_as_float(wbits << 16);
        float gbv = __uint_as_float(wbits & 0xffff0000u);
        float nm = fmaxf(m, L);
        float sc = (m > -INFINITY) ? __expf(m - nm) : 0.0f;
        float w  = __expf(L - nm);
        u0 = fmaf(u0, sc, w * ga);
        u1 = fmaf(u1, sc, w * gbv);
        z  = fmaf(z, sc, w);
        m = nm;
    }
    // merge the 16 groups (xor offs 4..32 preserve p bits)
    #pragma unroll
    for (int off = 4; off <= 32; off <<= 1) {
        float mo = __shfl_xor(m, off, 64);
        float zo = __shfl_xor(z, off, 64);
        float a0o = __shfl_xor(u0, off, 64);
        float a1o = __shfl_xor(u1, off, 64);
        float nm = fmaxf(m, mo);
        float a = (m  > -INFINITY) ? __expf(m  - nm) : 0.0f;
        float b = (mo > -INFINITY) ? __expf(mo - nm) : 0.0f;
        u0 = u0 * a + a0o * b;
        u1 = u1 * a + a1o * b;
        z  = z * a + zo * b;
        m = nm;
    }
    if (lane < 4) {
        float inv = (z > 0.0f) ? 1.0f / z : 0.0f;
        *(float2*)(feat + n * 16 + h * 8 + p * 2) = make_float2(u0 * inv, u1 * inv);
    }
}

// pooled[g][hc] += feat[n][hc]; run-length accumulation (batch sorted).
// thread = (segment of 16 nodes, channel); 40 blocks x 256.
__global__ __launch_bounds__(256) void k_pool(const float* __restrict__ feat,
        const int* __restrict__ batch, float* __restrict__ pooled) {
    __shared__ float sP[256];
    int t = threadIdx.x;
    sP[t] = 0.0f;
    __syncthreads();
    int tid = blockIdx.x * 256 + t;        // 0..10239
    int c = tid & 15, seg = tid >> 4;      // seg 0..639
    int n0 = seg * 16, n1 = min(n0 + 16, NN);
    float run = 0.0f;
    int curg = -1;
    for (int n = n0; n < n1; ++n) {
        int gg = batch[n];
        if (gg != curg) {
            if (curg >= 0) atomicAdd(&sP[curg * 16 + c], run);
            run = 0.0f; curg = gg;
        }
        run += feat[n * 16 + c];
    }
    if (curg >= 0) atomicAdd(&sP[curg * 16 + c], run);
    __syncthreads();
    atomicAdd(&pooled[t], sP[t]);
}

__global__ __launch_bounds__(512) void k_final(const float* __restrict__ pooled,
        const float* __restrict__ Wproj, const float* __restrict__ bproj,
        float* __restrict__ out) {
    int t = threadIdx.x;
    int g = t >> 5, fo = t & 31;
    float acc = bproj[fo];
    #pragma unroll
    for (int j = 0; j < 16; ++j) acc = fmaf(pooled[g * 16 + j], Wproj[j * 32 + fo], acc);
    out[g * 32 + fo] = acc;
}

extern "C" void kernel_launch(void* const* d_in, const int* in_sizes, int n_in,
                              void* d_out, int out_size, void* d_ws, size_t ws_size,
                              hipStream_t stream) {
    const float* nf    = (const float*)d_in[0];
    const float* pos   = (const float*)d_in[1];
    const float* We    = (const float*)d_in[2];
    const float* be    = (const float*)d_in[3];
    const float* Wq    = (const float*)d_in[4];
    const float* Wk    = (const float*)d_in[5];
    const float* W1    = (const float*)d_in[6];
    const float* b1    = (const float*)d_in[7];
    const float* Wa    = (const float*)d_in[8];
    const float* Wv    = (const float*)d_in[9];
    const float* Wo    = (const float*)d_in[10];
    const float* Wproj = (const float*)d_in[11];
    const float* bproj = (const float*)d_in[12];
    const int*   ei    = (const int*)d_in[13];
    const int*   batch = (const int*)d_in[14];
    float* out = (float*)d_out;
    (void)in_sizes; (void)n_in; (void)out_size; (void)ws_size;

    float* ws     = (float*)d_ws;
    float* x      = ws;                  // 160000
    float* q      = x + 160000;          // 320000
    float* k      = q + 320000;          // 320000
    float* feat   = k + 320000;          // 160000
    float* pooled = feat + 160000;       // 256
    int*   deg    = (int*)(pooled + 256);// 10000
    float* tab    = (float*)(deg + 10000);       // 2*2432 = 4864
    float* lgp    = tab + 4864;                  // 1,920,000
    unsigned* gbu = (unsigned*)(lgp + (size_t)NN * CAP * 2);  // 7,680,000 uints

    hipLaunchKernelGGL(k_xqk,    dim3(625),  dim3(256), 0, stream, nf, We, be, Wq, Wk, W1, b1, Wa, Wv, x, q, k, (int*)pooled, tab);
    hipLaunchKernelGGL(k_edge,   dim3(625),  dim3(256), 0, stream, pos, ei, q, k, Wo, x, tab, deg, lgp, (uint4*)gbu);
    hipLaunchKernelGGL(k_gather, dim3(5000), dim3(256), 0, stream, deg, lgp, gbu, feat);
    hipLaunchKernelGGL(k_pool,   dim3(40),   dim3(256), 0, stream, feat, batch, pooled);
    hipLaunchKernelGGL(k_final,  dim3(1),    dim3(512), 0, stream, pooled, Wproj, bproj, out);
}

// Round 2
// 138.651 us; speedup vs baseline: 1.0020x; 1.0020x over previous
//
#include <hip/hip_runtime.h>
#include <math.h>

#define NN 10000
#define NE 160000
#define CAP 96   // per-node edge bin capacity; deg ~ Poisson(16), +20 sigma
// Only the l=0 irrep reaches the output (scal takes cols h*72..h*72+8 of pooled,
// which come solely from node_out[:,:,0]; Y[:,0]==1). l=1/l=2 paths are dead.
//
// Round 9: structural fusion.
//  - k_pre: bin src-ids (4 B/edge, not 40 B payload) + x/q/k + PWL table build
//    (build parallelized: two-level prefix scan, no serial tail).
//  - k_node: per-target-node 32-lane group recomputes dot/PWL/g[8] inline with
//    online softmax in registers -> feat. lgp/gb intermediates GONE (full fp32).
//  - k_poolfinal: pooling + last-block-done final matmul (ticket pattern).
//  - deg/pooled/done zeroed by one hipMemsetAsync node.
// PWL math identical to Round 8 (hardware-validated): sum_j relu(a_j f+b_j)*w_j
// is piecewise-linear in f; per-segment A,B tables, 6-step branchless search.
//
// Table layout per head (floats, TPH=2832 stride), rows 16B-aligned:
//   [0..63]      sorted thresholds
//   [64..128]    Aatt[65]
//   [132..196]   Batt[65]
//   [200..1500)  A[65][20]  (stride 20 -> float4-aligned rows)
//   [1520..2820) B[65][20]
#define TPH 2832
#define AATT_OFF 64
#define BATT_OFF 132
#define A_OFF 200
#define B_OFF 1520

// Workspace (floats):
//   x      [10000][16]        @ 0
//   q      [10000][2][16]     @ 160000
//   k      [10000][2][16]     @ 480000
//   feat   [10000][16]        @ 800000
//   pooled [16][16]           @ 960000   \
//   deg    int[10000]         @ 960256    } zeroed by one memset (41,088 B)
//   done   int[16]            @ 970256   /
//   srcBin int[10000*96]      @ 970272
//   tab    [2][2832]          @ 1930272

// x = nf @ We + be ; q[h] = x @ Wq[h] ; k[h] = x @ Wk[h] ; bin edges;
// block 0 builds the piecewise-linear ReLU tables (parallel scan).
__global__ __launch_bounds__(256) void k_pre(const float* __restrict__ nf,
        const float* __restrict__ We, const float* __restrict__ be,
        const float* __restrict__ Wq, const float* __restrict__ Wk,
        const float* __restrict__ W1, const float* __restrict__ b1,
        const float* __restrict__ Wa, const float* __restrict__ Wv,
        const int* __restrict__ ei,
        float* __restrict__ x, float* __restrict__ q, float* __restrict__ k,
        int* __restrict__ deg, int* __restrict__ srcBin, float* __restrict__ tab) {
    int t = threadIdx.x;
    int gid = blockIdx.x * 256 + t;          // 625*256 == NE exactly
    {   // bin one edge: store src id only (4 B/edge)
        int s = ei[gid], tt = ei[NE + gid];
        int p = atomicAdd(&deg[tt], 1);
        if (p < CAP) srcBin[tt * CAP + p] = s;
    }
    __shared__ float sWe[64 * 16];
    __shared__ float sWq[2 * 16 * 16];
    __shared__ float sWk[2 * 16 * 16];
    __shared__ float sNF[16 * 64];
    __shared__ float sX[16 * 16];
    for (int i = t; i < 1024; i += 256) sWe[i] = We[i];
    for (int i = t; i < 512; i += 256) { sWq[i] = Wq[i]; sWk[i] = Wk[i]; }
    int nodeBase = blockIdx.x * 16;
    for (int i = t; i < 1024; i += 256) {
        int n = nodeBase + (i >> 6);
        sNF[i] = (n < NN) ? nf[n * 64 + (i & 63)] : 0.0f;
    }
    __syncthreads();
    int ln = t >> 4, c = t & 15;
    int n = nodeBase + ln;
    float acc = be[c];
    #pragma unroll 16
    for (int j = 0; j < 64; ++j) acc = fmaf(sNF[ln * 64 + j], sWe[j * 16 + c], acc);
    sX[ln * 16 + c] = acc;
    __syncthreads();
    if (n < NN) {
        x[n * 16 + c] = acc;
        #pragma unroll
        for (int h = 0; h < 2; ++h) {
            float aq = 0.0f, ak = 0.0f;
            #pragma unroll
            for (int j = 0; j < 16; ++j) {
                float xv = sX[ln * 16 + j];
                aq = fmaf(xv, sWq[(h * 16 + j) * 16 + c], aq);
                ak = fmaf(xv, sWk[(h * 16 + j) * 16 + c], ak);
            }
            q[(n * 2 + h) * 16 + c] = aq;
            k[(n * 2 + h) * 16 + c] = ak;
        }
    }
    if (blockIdx.x == 0) {
        __shared__ float sT[2][64], sDA[2][64], sDB[2][64], sIA[2][64], sIB[2][64];
        __shared__ float sW[2][64][17];   // per-unit channel weights; cc==16 -> Wa
        __shared__ short sOrd[2][64];
        __shared__ float sQA[2][17][4], sQB[2][17][4], sPA[2][17][4], sPB[2][17][4];
        // phase A: per-unit threshold + toggle deltas + init contributions
        if (t < 128) {
            int h = t >> 6, j = t & 63;
            float a = W1[h * 64 + j], b = b1[h * 64 + j];
            float da = 0.0f, db = 0.0f, ia = 0.0f, ib = 0.0f, th;
            if (a > 0.0f)      { th = -b / a; da = a;  db = b; }
            else if (a < 0.0f) { th = -b / a; da = -a; db = -b; ia = a; ib = b; }
            else               { th = INFINITY; if (b > 0.0f) ib = b; }
            sT[h][j] = th; sDA[h][j] = da; sDB[h][j] = db; sIA[h][j] = ia; sIB[h][j] = ib;
        }
        for (int i = t; i < 2 * 64 * 17; i += 256) {
            int h = i / 1088, r = i % 1088, j = r / 17, cc = r % 17;
            sW[h][j][cc] = (cc < 16) ? Wv[(h * 64 + j) * 48 + 3 * cc] : Wa[h * 64 + j];
        }
        __syncthreads();
        // phase B: rank-sort thresholds (64-wide O(n^2))
        if (t < 128) {
            int h = t >> 6, j = t & 63;
            float tj = sT[h][j];
            int r = 0;
            #pragma unroll 16
            for (int kk = 0; kk < 64; ++kk) {
                float tk = sT[h][kk];
                r += (tk < tj || (tk == tj && kk < j)) ? 1 : 0;
            }
            sOrd[h][r] = (short)j;
            tab[h * TPH + r] = tj;
        }
        __syncthreads();
        // phase C pass 1: per-(h,cc,quarter) partial sums (delta + init)
        int h = 0, cc = 0, qt = 0;
        bool act = (t < 136);
        if (act) { h = t / 68; int r = t % 68; cc = r >> 2; qt = r & 3; }
        float qsA = 0.f, qsB = 0.f, ipA = 0.f, ipB = 0.f;
        if (act) {
            #pragma unroll 4
            for (int i = 0; i < 16; ++i) {
                int r = qt * 16 + i;
                int u = sOrd[h][r];
                float w = sW[h][u][cc];
                qsA = fmaf(sDA[h][u], w, qsA);
                qsB = fmaf(sDB[h][u], w, qsB);
                float wj = sW[h][r][cc];      // init sum over original index partition
                ipA = fmaf(sIA[h][r], wj, ipA);
                ipB = fmaf(sIB[h][r], wj, ipB);
            }
            sQA[h][cc][qt] = qsA; sQB[h][cc][qt] = qsB;
            sPA[h][cc][qt] = ipA; sPB[h][cc][qt] = ipB;
        }
        __syncthreads();
        // phase C pass 2: prefix within quarter, store A/B per segment
        if (act) {
            float A = sPA[h][cc][0] + sPA[h][cc][1] + sPA[h][cc][2] + sPA[h][cc][3];
            float B = sPB[h][cc][0] + sPB[h][cc][1] + sPB[h][cc][2] + sPB[h][cc][3];
            for (int qq = 0; qq < qt; ++qq) { A += sQA[h][cc][qq]; B += sQB[h][cc][qq]; }
            float* pa; float* pb; int stride;
            if (cc == 16) { pa = tab + h * TPH + AATT_OFF; pb = tab + h * TPH + BATT_OFF; stride = 1; }
            else          { pa = tab + h * TPH + A_OFF + cc; pb = tab + h * TPH + B_OFF + cc; stride = 20; }
            #pragma unroll 4
            for (int i = 0; i < 16; ++i) {
                int r = qt * 16 + i;
                pa[r * stride] = A;
                pb[r * stride] = B;
                int u = sOrd[h][r];
                float w = sW[h][u][cc];
                A = fmaf(sDA[h][u], w, A);
                B = fmaf(sDB[h][u], w, B);
            }
            if (qt == 3) { pa[64 * stride] = A; pb[64 * stride] = B; }
        }
    }
}

// 32-lane group per target node (2 nodes/wave, 8 nodes/block): each lane owns
// one incoming-edge slot, computes dot/PWL/g[8] inline, online softmax in regs,
// 5-step xor merge, lane 0 writes feat[n][16]. No edge payload materialized.
__global__ __launch_bounds__(256) void k_node(const float* __restrict__ pos,
        const int* __restrict__ deg, const int* __restrict__ srcBin,
        const float* __restrict__ q, const float* __restrict__ kk,
        const float* __restrict__ x, const float* __restrict__ tab,
        const float* __restrict__ Wo, float* __restrict__ feat) {
    int t = threadIdx.x;
    int n = blockIdx.x * 8 + (t >> 5);     // 1250*8 == NN exactly
    int lane = t & 31;
    int dg = min(deg[n], CAP);
    float ptx = pos[n * 3 + 0], pty = pos[n * 3 + 1], ptz = pos[n * 3 + 2];
    const float4* qp = (const float4*)(q + (size_t)n * 32);
    float4 qv0 = qp[0], qv1 = qp[1], qv2 = qp[2], qv3 = qp[3];
    float4 qv4 = qp[4], qv5 = qp[5], qv6 = qp[6], qv7 = qp[7];
    float m[2] = { -INFINITY, -INFINITY };
    float z[2] = { 0.0f, 0.0f };
    float u[2][8];
    #pragma unroll
    for (int h = 0; h < 2; ++h)
        #pragma unroll
        for (int o = 0; o < 8; ++o) u[h][o] = 0.0f;
    for (int slot = lane; slot < dg; slot += 32) {
        int s = srcBin[n * CAP + slot];
        float dx = ptx - pos[s * 3 + 0];
        float dy = pty - pos[s * 3 + 1];
        float dz = ptz - pos[s * 3 + 2];
        float d = sqrtf(dx * dx + dy * dy + dz * dz);
        const float4* xp = (const float4*)(x + (size_t)s * 16);
        float4 xs0 = xp[0], xs1 = xp[1], xs2 = xp[2], xs3 = xp[3];
        float Xf[16] = { xs0.x, xs0.y, xs0.z, xs0.w, xs1.x, xs1.y, xs1.z, xs1.w,
                         xs2.x, xs2.y, xs2.z, xs2.w, xs3.x, xs3.y, xs3.z, xs3.w };
        #pragma unroll
        for (int h = 0; h < 2; ++h) {
            const float4* kp = (const float4*)(kk + (size_t)s * 32 + h * 16);
            float4 k0 = kp[0], k1 = kp[1], k2 = kp[2], k3 = kp[3];
            float4 a0 = h ? qv4 : qv0, a1 = h ? qv5 : qv1;
            float4 a2 = h ? qv6 : qv2, a3 = h ? qv7 : qv3;
            float dot = a0.x * k0.x + a0.y * k0.y + a0.z * k0.z + a0.w * k0.w
                      + a1.x * k1.x + a1.y * k1.y + a1.z * k1.z + a1.w * k1.w
                      + a2.x * k2.x + a2.y * k2.y + a2.z * k2.z + a2.w * k2.w
                      + a3.x * k3.x + a3.y * k3.y + a3.z * k3.z + a3.w * k3.w;
            float f = h ? 1.0f / (d * d) : d;
            const float* tb = tab + h * TPH;
            int sg = 0;
            #pragma unroll
            for (int st = 32; st >= 1; st >>= 1)
                if (tb[sg + st - 1] < f) sg += st;
            if (tb[sg] < f) ++sg;
            float att = fmaf(tb[AATT_OFF + sg], f, tb[BATT_OFF + sg]);
            float L = fmaf(dot, 0.25f, att);
            const float4* Ar = (const float4*)(tb + A_OFF + sg * 20);
            const float4* Br = (const float4*)(tb + B_OFF + sg * 20);
            float4 A0 = Ar[0], A1 = Ar[1], A2 = Ar[2], A3 = Ar[3];
            float4 B0 = Br[0], B1 = Br[1], B2 = Br[2], B3 = Br[3];
            float Af[16] = { A0.x, A0.y, A0.z, A0.w, A1.x, A1.y, A1.z, A1.w,
                             A2.x, A2.y, A2.z, A2.w, A3.x, A3.y, A3.z, A3.w };
            float Bf[16] = { B0.x, B0.y, B0.z, B0.w, B1.x, B1.y, B1.z, B1.w,
                             B2.x, B2.y, B2.z, B2.w, B3.x, B3.y, B3.z, B3.w };
            float g[8];
            #pragma unroll
            for (int o = 0; o < 8; ++o) g[o] = 0.0f;
            const float* wob = Wo + h * 384;   // Wo[h][0][c][o]
            #pragma unroll
            for (int c = 0; c < 16; ++c) {
                float ax = fmaf(Af[c], f, Bf[c]) * Xf[c];
                #pragma unroll
                for (int o = 0; o < 8; ++o) g[o] = fmaf(ax, wob[c * 8 + o], g[o]);
            }
            float nm = fmaxf(m[h], L);
            float sc = (m[h] > -INFINITY) ? __expf(m[h] - nm) : 0.0f;
            float w = __expf(L - nm);
            #pragma unroll
            for (int o = 0; o < 8; ++o) u[h][o] = fmaf(u[h][o], sc, w * g[o]);
            z[h] = fmaf(z[h], sc, w);
            m[h] = nm;
        }
    }
    // merge 32 lanes (xor 1..16 stays within the 32-lane group)
    #pragma unroll
    for (int h = 0; h < 2; ++h) {
        float mh = m[h], zh = z[h];
        #pragma unroll
        for (int off = 1; off <= 16; off <<= 1) {
            float mo = __shfl_xor(mh, off, 64);
            float zo = __shfl_xor(zh, off, 64);
            float uo[8];
            #pragma unroll
            for (int o = 0; o < 8; ++o) uo[o] = __shfl_xor(u[h][o], off, 64);
            float nm = fmaxf(mh, mo);
            float a = (mh > -INFINITY) ? __expf(mh - nm) : 0.0f;
            float b = (mo > -INFINITY) ? __expf(mo - nm) : 0.0f;
            #pragma unroll
            for (int o = 0; o < 8; ++o) u[h][o] = u[h][o] * a + uo[o] * b;
            zh = zh * a + zo * b;
            mh = nm;
        }
        if (lane == 0) {
            float inv = (zh > 0.0f) ? 1.0f / zh : 0.0f;
            float4* fp = (float4*)(feat + (size_t)n * 16 + h * 8);
            fp[0] = make_float4(u[h][0] * inv, u[h][1] * inv, u[h][2] * inv, u[h][3] * inv);
            fp[1] = make_float4(u[h][4] * inv, u[h][5] * inv, u[h][6] * inv, u[h][7] * inv);
        }
    }
}

// pooled[g][hc] += feat[n][hc] (run-length, batch sorted); last block to finish
// does the final 16x16 @ 16x32 matmul.
__global__ __launch_bounds__(256) void k_poolfinal(const float* __restrict__ feat,
        const int* __restrict__ batch, float* __restrict__ pooled,
        int* __restrict__ done, const float* __restrict__ Wproj,
        const float* __restrict__ bproj, float* __restrict__ out) {
    __shared__ float sP[256];
    int t = threadIdx.x;
    sP[t] = 0.0f;
    __syncthreads();
    int tid = blockIdx.x * 256 + t;        // 0..10239
    int c = tid & 15, seg = tid >> 4;      // seg 0..639
    int n0 = seg * 16, n1 = min(n0 + 16, NN);
    float run = 0.0f;
    int curg = -1;
    for (int n = n0; n < n1; ++n) {
        int gg = batch[n];
        if (gg != curg) {
            if (curg >= 0) atomicAdd(&sP[curg * 16 + c], run);
            run = 0.0f; curg = gg;
        }
        run += feat[n * 16 + c];
    }
    if (curg >= 0) atomicAdd(&sP[curg * 16 + c], run);
    __syncthreads();
    atomicAdd(&pooled[t], sP[t]);
    __threadfence();
    __shared__ int lastBlk;
    if (t == 0) lastBlk = (atomicAdd(done, 1) == 39) ? 1 : 0;
    __syncthreads();
    if (!lastBlk) return;
    __threadfence();
    __shared__ float sPool[256];
    sPool[t] = atomicAdd(&pooled[t], 0.0f);   // forced L2 read of final values
    __syncthreads();
    for (int i = t; i < 512; i += 256) {
        int g = i >> 5, fo = i & 31;
        float acc = bproj[fo];
        #pragma unroll
        for (int j = 0; j < 16; ++j) acc = fmaf(sPool[g * 16 + j], Wproj[j * 32 + fo], acc);
        out[g * 32 + fo] = acc;
    }
}

extern "C" void kernel_launch(void* const* d_in, const int* in_sizes, int n_in,
                              void* d_out, int out_size, void* d_ws, size_t ws_size,
                              hipStream_t stream) {
    const float* nf    = (const float*)d_in[0];
    const float* pos   = (const float*)d_in[1];
    const float* We    = (const float*)d_in[2];
    const float* be    = (const float*)d_in[3];
    const float* Wq    = (const float*)d_in[4];
    const float* Wk    = (const float*)d_in[5];
    const float* W1    = (const float*)d_in[6];
    const float* b1    = (const float*)d_in[7];
    const float* Wa    = (const float*)d_in[8];
    const float* Wv    = (const float*)d_in[9];
    const float* Wo    = (const float*)d_in[10];
    const float* Wproj = (const float*)d_in[11];
    const float* bproj = (const float*)d_in[12];
    const int*   ei    = (const int*)d_in[13];
    const int*   batch = (const int*)d_in[14];
    float* out = (float*)d_out;
    (void)in_sizes; (void)n_in; (void)out_size; (void)ws_size;

    float* ws     = (float*)d_ws;
    float* x      = ws;                    // 160000
    float* q      = x + 160000;            // 320000
    float* k      = q + 320000;            // 320000
    float* feat   = k + 320000;            // 160000
    float* pooled = feat + 160000;         // 256
    int*   deg    = (int*)(pooled + 256);  // 10000
    int*   done   = deg + 10000;           // 16 (pad)
    int*   srcBin = done + 16;             // 960000
    float* tab    = (float*)(srcBin + 960000);   // 2*2832

    // zero pooled + deg + done in one memset node (contiguous, 41,088 B)
    hipMemsetAsync(pooled, 0, (256 + 10000 + 16) * sizeof(int), stream);
    hipLaunchKernelGGL(k_pre,       dim3(625),  dim3(256), 0, stream,
                       nf, We, be, Wq, Wk, W1, b1, Wa, Wv, ei, x, q, k, deg, srcBin, tab);
    hipLaunchKernelGGL(k_node,      dim3(1250), dim3(256), 0, stream,
                       pos, deg, srcBin, q, k, x, tab, Wo, feat);
    hipLaunchKernelGGL(k_poolfinal, dim3(40),   dim3(256), 0, stream,
                       feat, batch, pooled, done, Wproj, bproj, out);
}

// Round 3
// 131.754 us; speedup vs baseline: 1.0545x; 1.0523x over previous
//
#include <hip/hip_runtime.h>
#include <math.h>

#define NN 10000
#define NE 160000
#define CAP 96   // per-node edge bin capacity; deg ~ Poisson(16), +20 sigma
// Only the l=0 irrep reaches the output (scal takes cols h*72..h*72+8 of pooled,
// which come solely from node_out[:,:,0]; Y[:,0]==1). l=1/l=2 paths are dead.
//
// Round 10: REVERT to the Round-7 structure (130.6 us, reproduced twice).
// The PWL-table variants (R8: 138.9, R9: 138.7) are a reproducible -8 us
// regression in two embodiments -> table build critical path + dependent
// table-gather chains cost more than the brute-force uniform-scalar MLP
// (which compiles to pipelined s_loads). Only retained R9 innovation:
// k_pool + k_final fused via last-block ticket (validated in R9), 5->4 launches.
//
// Workspace (floats):
//   x      [10000][16]        @ 0
//   q      [10000][2][16]     @ 160000
//   k      [10000][2][16]     @ 480000
//   feat   [10000][16]        @ 800000
//   pooled [16][16]           @ 960000
//   deg    int[10000]         @ 960256   (pooled..deg..done zeroed together)
//   done   int[16]            @ 970256
//   vC     [2][64][16]        @ 970272   (compacted Wv[:, ::3])
//   lgp    [10000][96][2]     fp32 logits
//   gb     [10000][96][2][4]  uint bf16x2-packed g[8] per head

__device__ __forceinline__ unsigned bf16pack2(float a, float b) {
    unsigned ua = __float_as_uint(a);
    unsigned ub = __float_as_uint(b);
    ua = ua + 0x7fffu + ((ua >> 16) & 1u);
    ub = ub + 0x7fffu + ((ub >> 16) & 1u);
    return (ua >> 16) | (ub & 0xffff0000u);
}

// x = nf @ We + be ; q[h] = x @ Wq[h] ; k[h] = x @ Wk[h]
// block 0 also compacts Wv -> vC; all blocks zero pooled+deg+done.
__global__ __launch_bounds__(256) void k_xqk(const float* __restrict__ nf,
        const float* __restrict__ We, const float* __restrict__ be,
        const float* __restrict__ Wq, const float* __restrict__ Wk,
        const float* __restrict__ Wv,
        float* __restrict__ x, float* __restrict__ q, float* __restrict__ k,
        int* __restrict__ zeroReg, float* __restrict__ vC) {
    int t = threadIdx.x;
    int gid = blockIdx.x * 256 + t;
    if (gid < 10272) zeroReg[gid] = 0;   // pooled(256f)+deg(10000i)+done(16i)
    if (blockIdx.x == 0) {
        for (int i = t; i < 2048; i += 256) {
            int h = i >> 10, j = (i >> 4) & 63, c = i & 15;
            vC[i] = Wv[(h * 64 + j) * 48 + 3 * c];
        }
    }
    __shared__ float sWe[64 * 16];
    __shared__ float sWq[2 * 16 * 16];
    __shared__ float sWk[2 * 16 * 16];
    __shared__ float sNF[16 * 64];
    __shared__ float sX[16 * 16];
    for (int i = t; i < 1024; i += 256) sWe[i] = We[i];
    for (int i = t; i < 512; i += 256) { sWq[i] = Wq[i]; sWk[i] = Wk[i]; }
    int nodeBase = blockIdx.x * 16;
    for (int i = t; i < 1024; i += 256) {
        int n = nodeBase + (i >> 6);
        sNF[i] = (n < NN) ? nf[n * 64 + (i & 63)] : 0.0f;
    }
    __syncthreads();
    int ln = t >> 4, c = t & 15;
    int n = nodeBase + ln;
    float acc = be[c];
    #pragma unroll 16
    for (int j = 0; j < 64; ++j) acc = fmaf(sNF[ln * 64 + j], sWe[j * 16 + c], acc);
    sX[ln * 16 + c] = acc;
    __syncthreads();
    if (n < NN) {
        x[n * 16 + c] = acc;
        #pragma unroll
        for (int h = 0; h < 2; ++h) {
            float aq = 0.0f, ak = 0.0f;
            #pragma unroll
            for (int j = 0; j < 16; ++j) {
                float xv = sX[ln * 16 + j];
                aq = fmaf(xv, sWq[(h * 16 + j) * 16 + c], aq);
                ak = fmaf(xv, sWk[(h * 16 + j) * 16 + c], ak);
            }
            q[(n * 2 + h) * 16 + c] = aq;
            k[(n * 2 + h) * 16 + c] = ak;
        }
    }
}

// one thread per edge: logits + g[o] = ((hid@V) * x[src]) @ Wo, bin slot tgt*CAP+p.
// Weight reads are lane-invariant -> scalar s_loads. Payload bf16x2-packed.
__global__ __launch_bounds__(256) void k_edge(const float* __restrict__ pos,
        const int* __restrict__ ei,
        const float* __restrict__ q, const float* __restrict__ k,
        const float* __restrict__ W1, const float* __restrict__ b1,
        const float* __restrict__ Wa, const float* __restrict__ vC,
        const float* __restrict__ Wo,
        const float* __restrict__ x, int* __restrict__ deg,
        float* __restrict__ lgp, uint4* __restrict__ gb) {
    int e = blockIdx.x * 256 + threadIdx.x;
    if (e >= NE) return;
    int s = ei[e], t = ei[NE + e];
    int p = atomicAdd(&deg[t], 1);
    bool ok = (p < CAP);
    size_t slot = (size_t)t * CAP + p;
    float dx = pos[t * 3 + 0] - pos[s * 3 + 0];
    float dy = pos[t * 3 + 1] - pos[s * 3 + 1];
    float dz = pos[t * 3 + 2] - pos[s * 3 + 2];
    float d = sqrtf(dx * dx + dy * dy + dz * dz);
    float fh[2] = { d, 1.0f / (d * d) };
    const float4* xp = (const float4*)(x + (size_t)s * 16);
    float4 xs0 = xp[0], xs1 = xp[1], xs2 = xp[2], xs3 = xp[3];
    float xf[16] = { xs0.x, xs0.y, xs0.z, xs0.w, xs1.x, xs1.y, xs1.z, xs1.w,
                     xs2.x, xs2.y, xs2.z, xs2.w, xs3.x, xs3.y, xs3.z, xs3.w };
    float L2v[2];
    #pragma unroll
    for (int h = 0; h < 2; ++h) {
        const float4* qt = (const float4*)(q + (size_t)t * 32 + h * 16);
        const float4* ks = (const float4*)(k + (size_t)s * 32 + h * 16);
        float4 a0 = qt[0], a1 = qt[1], a2 = qt[2], a3 = qt[3];
        float4 b0 = ks[0], c1 = ks[1], c2 = ks[2], c3 = ks[3];
        float dot = a0.x * b0.x + a0.y * b0.y + a0.z * b0.z + a0.w * b0.w
                  + a1.x * c1.x + a1.y * c1.y + a1.z * c1.z + a1.w * c1.w
                  + a2.x * c2.x + a2.y * c2.y + a2.z * c2.z + a2.w * c2.w
                  + a3.x * c3.x + a3.y * c3.y + a3.z * c3.z + a3.w * c3.w;
        float f = fh[h];
        float att = 0.0f;
        float acc[16];
        #pragma unroll
        for (int c = 0; c < 16; ++c) acc[c] = 0.0f;
        const float* w1b = W1 + h * 64;
        const float* b1b = b1 + h * 64;
        const float* wab = Wa + h * 64;
        const float* vcb = vC + h * 1024;
        #pragma unroll 8
        for (int j = 0; j < 64; ++j) {
            float hid = fmaxf(fmaf(f, w1b[j], b1b[j]), 0.0f);   // uniform scalars
            att = fmaf(hid, wab[j], att);
            #pragma unroll
            for (int c = 0; c < 16; ++c)
                acc[c] = fmaf(hid, vcb[j * 16 + c], acc[c]);     // uniform scalars
        }
        L2v[h] = fmaf(dot, 0.25f, att);
        // project to 8 outputs through Wo[h][0] (uniform scalars)
        float g[8];
        #pragma unroll
        for (int o = 0; o < 8; ++o) g[o] = 0.0f;
        const float* wob = Wo + h * 384;   // Wo[h][0][c][o] = Wo[h*384 + c*8 + o]
        #pragma unroll
        for (int c = 0; c < 16; ++c) {
            float axc = acc[c] * xf[c];
            #pragma unroll
            for (int o = 0; o < 8; ++o) g[o] = fmaf(axc, wob[c * 8 + o], g[o]);
        }
        if (ok) {
            gb[slot * 2 + h] = make_uint4(bf16pack2(g[0], g[1]), bf16pack2(g[2], g[3]),
                                          bf16pack2(g[4], g[5]), bf16pack2(g[6], g[7]));
        }
    }
    if (ok) *(float2*)(lgp + slot * 2) = make_float2(L2v[0], L2v[1]);
}

// wave per (node,head): 16 edge-groups x 4 lanes x 2 outputs (bf16x2 unpack),
// single-pass online softmax, -inf-safe merges.
__global__ __launch_bounds__(256) void k_gather(const int* __restrict__ deg,
        const float* __restrict__ lgp, const unsigned* __restrict__ gb,
        float* __restrict__ feat) {
    int t0 = threadIdx.x;
    int wv = t0 >> 6;                     // wave in block 0..3
    int lane = t0 & 63;
    int pid = blockIdx.x * 4 + wv;        // (node,head) pair; grid exact
    int n = pid >> 1, h = pid & 1;
    int dg = min(deg[n], CAP);
    int g = lane >> 2, p = lane & 3;      // group 0..15, uint index 0..3
    float m = -INFINITY, z = 0.0f, u0 = 0.0f, u1 = 0.0f;
    const float* lgb = lgp + (size_t)n * (CAP * 2) + h;
    const unsigned* gbb = gb + (size_t)n * (CAP * 8) + h * 4 + p;
    for (int i = g; i < dg; i += 16) {
        float L = lgb[i * 2];
        unsigned wbits = gbb[(size_t)i * 8];
        float ga = __uint_as_float(wbits << 16);
        float gbv = __uint_as_float(wbits & 0xffff0000u);
        float nm = fmaxf(m, L);
        float sc = (m > -INFINITY) ? __expf(m - nm) : 0.0f;
        float w  = __expf(L - nm);
        u0 = fmaf(u0, sc, w * ga);
        u1 = fmaf(u1, sc, w * gbv);
        z  = fmaf(z, sc, w);
        m = nm;
    }
    // merge the 16 groups (xor offs 4..32 preserve p bits)
    #pragma unroll
    for (int off = 4; off <= 32; off <<= 1) {
        float mo = __shfl_xor(m, off, 64);
        float zo = __shfl_xor(z, off, 64);
        float a0o = __shfl_xor(u0, off, 64);
        float a1o = __shfl_xor(u1, off, 64);
        float nm = fmaxf(m, mo);
        float a = (m  > -INFINITY) ? __expf(m  - nm) : 0.0f;
        float b = (mo > -INFINITY) ? __expf(mo - nm) : 0.0f;
        u0 = u0 * a + a0o * b;
        u1 = u1 * a + a1o * b;
        z  = z * a + zo * b;
        m = nm;
    }
    if (lane < 4) {
        float inv = (z > 0.0f) ? 1.0f / z : 0.0f;
        *(float2*)(feat + n * 16 + h * 8 + p * 2) = make_float2(u0 * inv, u1 * inv);
    }
}

// pooled[g][hc] += feat[n][hc] (run-length, batch sorted); last block to finish
// does the final 16x16 @ 16x32 matmul (ticket pattern, validated in R9).
__global__ __launch_bounds__(256) void k_poolfinal(const float* __restrict__ feat,
        const int* __restrict__ batch, float* __restrict__ pooled,
        int* __restrict__ done, const float* __restrict__ Wproj,
        const float* __restrict__ bproj, float* __restrict__ out) {
    __shared__ float sP[256];
    int t = threadIdx.x;
    sP[t] = 0.0f;
    __syncthreads();
    int tid = blockIdx.x * 256 + t;        // 0..10239
    int c = tid & 15, seg = tid >> 4;      // seg 0..639
    int n0 = seg * 16, n1 = min(n0 + 16, NN);
    float run = 0.0f;
    int curg = -1;
    for (int n = n0; n < n1; ++n) {
        int gg = batch[n];
        if (gg != curg) {
            if (curg >= 0) atomicAdd(&sP[curg * 16 + c], run);
            run = 0.0f; curg = gg;
        }
        run += feat[n * 16 + c];
    }
    if (curg >= 0) atomicAdd(&sP[curg * 16 + c], run);
    __syncthreads();
    atomicAdd(&pooled[t], sP[t]);
    __threadfence();
    __shared__ int lastBlk;
    if (t == 0) lastBlk = (atomicAdd(done, 1) == 39) ? 1 : 0;
    __syncthreads();
    if (!lastBlk) return;
    __shared__ float sPool[256];
    sPool[t] = atomicAdd(&pooled[t], 0.0f);   // coherent read of final values
    __syncthreads();
    for (int i = t; i < 512; i += 256) {
        int g = i >> 5, fo = i & 31;
        float acc = bproj[fo];
        #pragma unroll
        for (int j = 0; j < 16; ++j) acc = fmaf(sPool[g * 16 + j], Wproj[j * 32 + fo], acc);
        out[g * 32 + fo] = acc;
    }
}

extern "C" void kernel_launch(void* const* d_in, const int* in_sizes, int n_in,
                              void* d_out, int out_size, void* d_ws, size_t ws_size,
                              hipStream_t stream) {
    const float* nf    = (const float*)d_in[0];
    const float* pos   = (const float*)d_in[1];
    const float* We    = (const float*)d_in[2];
    const float* be    = (const float*)d_in[3];
    const float* Wq    = (const float*)d_in[4];
    const float* Wk    = (const float*)d_in[5];
    const float* W1    = (const float*)d_in[6];
    const float* b1    = (const float*)d_in[7];
    const float* Wa    = (const float*)d_in[8];
    const float* Wv    = (const float*)d_in[9];
    const float* Wo    = (const float*)d_in[10];
    const float* Wproj = (const float*)d_in[11];
    const float* bproj = (const float*)d_in[12];
    const int*   ei    = (const int*)d_in[13];
    const int*   batch = (const int*)d_in[14];
    float* out = (float*)d_out;
    (void)in_sizes; (void)n_in; (void)out_size; (void)ws_size;

    float* ws     = (float*)d_ws;
    float* x      = ws;                  // 160000
    float* q      = x + 160000;          // 320000
    float* k      = q + 320000;          // 320000
    float* feat   = k + 320000;          // 160000
    float* pooled = feat + 160000;       // 256
    int*   deg    = (int*)(pooled + 256);// 10000
    int*   done   = deg + 10000;         // 16
    float* vC     = (float*)(done + 16);         // 2048
    float* lgp    = vC + 2048;                   // 1,920,000
    unsigned* gbu = (unsigned*)(lgp + (size_t)NN * CAP * 2);  // 7,680,000 uints

    hipLaunchKernelGGL(k_xqk,      dim3(625),  dim3(256), 0, stream,
                       nf, We, be, Wq, Wk, Wv, x, q, k, (int*)pooled, vC);
    hipLaunchKernelGGL(k_edge,     dim3(625),  dim3(256), 0, stream,
                       pos, ei, q, k, W1, b1, Wa, vC, Wo, x, deg, lgp, (uint4*)gbu);
    hipLaunchKernelGGL(k_gather,   dim3(5000), dim3(256), 0, stream,
                       deg, lgp, gbu, feat);
    hipLaunchKernelGGL(k_poolfinal, dim3(40),  dim3(256), 0, stream,
                       feat, batch, pooled, done, Wproj, bproj, out);
}